// Round 15
// baseline (4320.010 us; speedup 1.0000x reference)
//
#include <hip/hip_runtime.h>
#include <math.h>

#define BB 2048
#define TT 512
#define NFEAT 25
#define UNITS 300
#define RPB 16
#define NBLK (BB/RPB)    // 128
#define NT 512
#define KS12 12          // fp8 B stream: ks0-1 = W2K (gates), ks2-11 = wr (h)
#define NKS 11           // heads B k-steps (ks0 skipped)
#define TPW 10           // tiles per wave (80 tiles / 8 waves)
#define HROW 360         // Hbf row stride (shorts); h at cols 32..331
#define F8ROW 392        // Af8 row stride (bytes); h at 64..363
#define GROW 72

// d_ws layout (short offsets)
#define OFF_M1 0
#define SZ_M1  (4*2*512)             // 4096
#define OFF_H  (OFF_M1 + SZ_M1)
#define SZ_H   (2*NKS*512)           // 11264
#define OFF_BZ (OFF_H + SZ_H)        // 1280 floats = 2560 shorts
#define OFF_WK (OFF_BZ + 2560)       // 1280 floats
#define OFF_F8 (OFF_WK + 2560)       // byte region begins here
#define SZ_F8B (8*KS12*TPW*512)      // 491520 bytes
#define SW_SZ  (SZ_M1 + SZ_H)
#define SWM1   0
#define SWH    (SZ_M1)

typedef __attribute__((ext_vector_type(4))) float f32x4;
typedef __attribute__((ext_vector_type(8))) short bf16x8;
typedef long long ll8;

static __device__ __forceinline__ unsigned short f2bf(float f) {
    union { float f; unsigned u; } x; x.f = f;
    unsigned r = (x.u + 0x7fffu + ((x.u >> 16) & 1u)) >> 16;
    return (unsigned short)r;
}
static __device__ __forceinline__ unsigned char f2f8(float f) {
    return (unsigned char)(__builtin_amdgcn_cvt_pk_fp8_f32(f, 0.f, 0, false) & 0xff);
}
static __device__ __forceinline__ float ftanh(float v) {
    float e = __builtin_amdgcn_exp2f(v * 2.8853900817779268f);
    return 1.f - 2.f * __builtin_amdgcn_rcpf(e + 1.f);
}
static __device__ __forceinline__ int zcol(int c) { return (c & 3) * 300 + (c >> 2); }

// unified fp8 B: [wave][ks0-11][tile][512] bytes.
// ks0-1: 8*W2K rows k=0..49 (W2K = w2 @ wk[0:24]); ks2-11: wr rows u = k-64.
__global__ __launch_bounds__(256) void conv_b8(
    const float* __restrict__ wk, const float* __restrict__ wr,
    const float* __restrict__ w2, unsigned char* __restrict__ dst8)
{
    int idx = blockIdx.x * 256 + threadIdx.x;
    if (idx >= SZ_F8B) return;
    int j = idx & 7, n = (idx >> 3) & 15, kg = (idx >> 7) & 3, q = idx >> 9;
    int i = q % TPW, ks = (q / TPW) % KS12, w = q / (TPW * KS12);
    int k = ks * 32 + kg * 8 + j, c = (w + 8 * i) * 16 + n;
    float v = 0.f;
    if (c < 1200) {
        int oc = zcol(c);
        if (ks < 2) {
            if (k < 50) {
                float s = 0.f;
                for (int j2 = 0; j2 < 24; ++j2)
                    s += w2[k * 24 + j2] * wk[j2 * 1200 + oc];
                v = 8.f * s;
            }
        } else {
            int u = k - 64;
            if (u < 300) v = wr[u * 1200 + oc];
        }
    }
    dst8[idx] = f2f8(v);
}

// bz' = bz + b2 @ wk[0:24]  and  wk24 row, both in zcol order
__global__ __launch_bounds__(256) void conv_misc(
    const float* __restrict__ wk, const float* __restrict__ bz,
    const float* __restrict__ b2, float* __restrict__ bzdst,
    float* __restrict__ wkdst)
{
    int i = blockIdx.x * 256 + threadIdx.x;
    if (i >= 1280) return;
    float vb = 0.f, vw = 0.f;
    if (i < 1200) {
        int oc = zcol(i);
        vb = bz[oc];
        for (int j = 0; j < 24; ++j) vb += b2[j] * wk[j * 1200 + oc];
        vw = wk[24 * 1200 + oc];
    }
    bzdst[i] = vb;
    wkdst[i] = vw;
}

__global__ __launch_bounds__(256) void conv_gen(
    const float* __restrict__ W, unsigned short* __restrict__ dst,
    int K, int N, int nks, int total)
{
    int idx = blockIdx.x * 256 + threadIdx.x;
    if (idx >= total) return;
    int j = idx & 7, n = (idx >> 3) & 15, kg = (idx >> 7) & 3, qq = idx >> 9;
    int ks = qq % nks, nt = qq / nks;
    int k = ks * 32 + kg * 8 + j, col = nt * 16 + n;
    float v = (k < K && col < N) ? W[k * N + col] : 0.f;
    dst[idx] = f2bf(v);
}

// heads B: K'=352, h at k=32..331 (u=k-32); ks0 all zero (skipped)
__global__ __launch_bounds__(256) void conv_heads(
    const float* __restrict__ wa, const float* __restrict__ wm,
    const float* __restrict__ wsg, unsigned short* __restrict__ dst)
{
    int idx = blockIdx.x * 256 + threadIdx.x;
    if (idx >= SZ_H) return;
    int j = idx & 7, n = (idx >> 3) & 15, kg = (idx >> 7) & 3, qq = idx >> 9;
    int ks = qq % NKS, nt = qq / NKS;
    int k = ks * 32 + kg * 8 + j, col = nt * 16 + n;
    float v = 0.f;
    if (k >= 32 && k < 332 && col < 24) {
        int u = k - 32, h = col >> 3, m = col & 7;
        const float* W = (h == 0) ? wa : (h == 1) ? wm : wsg;
        v = W[u * 8 + m];
    }
    dst[idx] = f2bf(v);
}

#define MFMA   __builtin_amdgcn_mfma_f32_16x16x32_bf16
#define MFMA8  __builtin_amdgcn_mfma_f32_16x16x32_fp8_fp8

__global__ __launch_bounds__(NT, 2)
void dilstm(
    const float* __restrict__ x,
    const unsigned short* __restrict__ wf,
    const float* __restrict__ b1v,
    const float* __restrict__ ba,
    const float* __restrict__ bm,
    const float* __restrict__ bs,
    float* __restrict__ out)
{
    __shared__ unsigned short Hbf[RPB][HROW];              // bf16 h (heads A), cols 32..331
    __shared__ __attribute__((aligned(16))) unsigned char Af8[RPB][F8ROW]; // fp8 h, cols 64..363
    __shared__ __attribute__((aligned(16))) unsigned char G1b8[RPB][64];   // fp8 relu1/8, cols 0..49
    __shared__ unsigned short Gbf[RPB][GROW];              // gate-MLP input (bf16)
    __shared__ float Sc[RPB][24];
    __shared__ float BzS[1280];                            // bz' in zcol order
    __shared__ float WkS[1280];                            // wk[24] in zcol order
    __shared__ float CombS[RPB];
    __shared__ float B1S[64];
    __shared__ float Zw[8][2][16][20];                     // per-wave z staging (dbuf)
    __shared__ unsigned short SW[SW_SZ];                   // MLP1 | heads weights

    const int t = threadIdx.x;
    const int lane = t & 63, wv = t >> 6;
    const int arow = lane & 15, akg = lane >> 4;
    const int crow0 = akg * 4;
    const int u_l = lane & 3, rr = lane >> 2;
    const int row0 = blockIdx.x * RPB;

    for (int i = t; i < RPB * HROW; i += NT) ((unsigned short*)Hbf)[i] = 0;
    for (int i = t; i < RPB * F8ROW; i += NT) ((unsigned char*)Af8)[i] = 0;
    for (int i = t; i < RPB * 64; i += NT) ((unsigned char*)G1b8)[i] = 0;
    for (int i = t; i < RPB * GROW; i += NT) ((unsigned short*)Gbf)[i] = 0;
    for (int i = t; i < SW_SZ; i += NT) SW[i] = wf[OFF_M1 + i];
    {
        const float* bzp = (const float*)(wf + OFF_BZ);
        const float* wkp = (const float*)(wf + OFF_WK);
        for (int i = t; i < 1280; i += NT) { BzS[i] = bzp[i]; WkS[i] = wkp[i]; }
    }
    if (t < 64) B1S[t] = (t < 50) ? b1v[t] : 0.f;

    float hbias = 0.f;
    {
        int c1 = wv * 16 + arow;
        if (wv < 2 && c1 < 24)
            hbias = (c1 < 8) ? ba[c1] : (c1 < 16) ? bm[c1 - 8] : bs[c1 - 16];
    }

    float creg[TPW];
    #pragma unroll
    for (int i = 0; i < TPW; ++i) creg[i] = 0.f;

    const unsigned char* bw8 = (const unsigned char*)(wf + OFF_F8)
                               + (size_t)wv * (KS12 * TPW * 512) + (lane << 3);
    const unsigned char* af8p = &Af8[0][0] + arow * F8ROW + akg * 8;

    const int rA = t / 25, eA = t - (t / 25) * 25;
    float combreg = 0.f, xreg = 0.f;
    if (t < RPB * NFEAT) xreg = x[((size_t)(row0 + rA) * TT) * NFEAT + eA];
    __syncthreads();

    // initial gate-input build (prev = 0)
    if (t < RPB * NFEAT) {
        if (eA < 24) {
            Gbf[rA][eA] = f2bf(xreg);
        } else {
            float comb = xreg;
            combreg = comb;
            float denom = fmaxf(comb, 1e-8f);
            Gbf[rA][24] = f2bf(xreg / denom);
            CombS[rA] = comb;
        }
    }
    __syncthreads();

    for (int ts = 0; ts < TT; ++ts) {
        // ========== P1: MLP1 (waves 0-3, 1 tile each) || h-part ks2-11 (all) ==========
        f32x4 acc[TPW];
        #pragma unroll
        for (int i = 0; i < TPW; ++i) acc[i] = (f32x4){0.f, 0.f, 0.f, 0.f};

        if (wv < 4) {
            bf16x8 ga0 = *(const bf16x8*)&Gbf[arow][akg * 8];
            bf16x8 ga1 = *(const bf16x8*)&Gbf[arow][32 + akg * 8];
            bf16x8 b0 = *(const bf16x8*)&SW[SWM1 + (wv * 2 + 0) * 512 + (lane << 3)];
            bf16x8 b1 = *(const bf16x8*)&SW[SWM1 + (wv * 2 + 1) * 512 + (lane << 3)];
            f32x4 m1 = {0.f, 0.f, 0.f, 0.f};
            m1 = MFMA(ga0, b0, m1, 0, 0, 0);
            m1 = MFMA(ga1, b1, m1, 0, 0, 0);
            int col = wv * 16 + arow;
            if (col < 50) {
                #pragma unroll
                for (int rg = 0; rg < 4; ++rg)
                    G1b8[crow0 + rg][col] = f2f8(0.125f * fmaxf(m1[rg] + B1S[col], 0.f));
            }
        }

        // x prefetch: HBM latency drains under the GEMM
        if (t < RPB * NFEAT && ts + 1 < TT)
            xreg = x[((size_t)(row0 + rA) * TT + (ts + 1)) * NFEAT + eA];

        // fp8 h-part (ks2-11), software-pipelined depth 2, one running pointer
        {
            const unsigned char* bp = bw8 + 2 * (TPW * 512);
            ll8 bbA[TPW], bbB[TPW];
            #pragma unroll
            for (int i = 0; i < TPW; ++i)
                bbA[i] = *(const ll8*)(bp + i * 512);
            #pragma unroll 1
            for (int pr = 0; pr < 5; ++pr) {
                const int ks = 2 * pr + 2;
                #pragma unroll
                for (int i = 0; i < TPW; ++i)
                    bbB[i] = *(const ll8*)(bp + 5120 + i * 512);
                ll8 a8a = *(const ll8*)(af8p + ks * 32);
                #pragma unroll
                for (int i = 0; i < TPW; ++i)
                    acc[i] = MFMA8(a8a, bbA[i], acc[i], 0, 0, 0);
                if (pr < 4) {
                    #pragma unroll
                    for (int i = 0; i < TPW; ++i)
                        bbA[i] = *(const ll8*)(bp + 10240 + i * 512);
                }
                ll8 a8b = *(const ll8*)(af8p + ks * 32 + 32);
                #pragma unroll
                for (int i = 0; i < TPW; ++i)
                    acc[i] = MFMA8(a8b, bbB[i], acc[i], 0, 0, 0);
                bp += 10240;
            }
        }
        __syncthreads();

        // ========== P2: gates ks0-1 (relu1/8 @ 8*W2K) + epilogue/cell -> h ==========
        {
            ll8 g0 = *(const ll8*)&G1b8[arow][akg * 8];
            ll8 g1 = *(const ll8*)&G1b8[arow][32 + akg * 8];
            ll8 c0[TPW], c1[TPW];
            #pragma unroll
            for (int i = 0; i < TPW; ++i) c0[i] = *(const ll8*)(bw8 + i * 512);
            #pragma unroll
            for (int i = 0; i < TPW; ++i) c1[i] = *(const ll8*)(bw8 + 5120 + i * 512);
            #pragma unroll
            for (int i = 0; i < TPW; ++i) acc[i] = MFMA8(g0, c0[i], acc[i], 0, 0, 0);
            #pragma unroll
            for (int i = 0; i < TPW; ++i) acc[i] = MFMA8(g1, c1[i], acc[i], 0, 0, 0);

            // epilogue: LDS gate-regroup + bias + comb*wk24 + cell
            float cmb = CombS[rr];
            *(f32x4*)&Zw[wv][0][arow][crow0] = acc[0];
            #pragma unroll
            for (int i = 0; i < TPW; ++i) {
                if (i + 1 < TPW)
                    *(f32x4*)&Zw[wv][(i + 1) & 1][arow][crow0] = acc[i + 1];
                f32x4 bz4 = *(const f32x4*)&BzS[(wv + 8 * i) * 16 + 4 * u_l];
                f32x4 wk4 = *(const f32x4*)&WkS[(wv + 8 * i) * 16 + 4 * u_l];
                const float* zp = &Zw[wv][i & 1][4 * u_l][rr];
                float zi = zp[0]  + bz4[0] + cmb * wk4[0];
                float zf = zp[20] + bz4[1] + cmb * wk4[1];
                float zc = zp[40] + bz4[2] + cmb * wk4[2];
                float zo = zp[60] + bz4[3] + cmb * wk4[3];
                if (wv + 8 * i < 75) {
                    float ig = fminf(fmaxf(0.2f * zi + 0.5f, 0.f), 1.f);
                    float fg = fminf(fmaxf(0.2f * zf + 0.5f, 0.f), 1.f);
                    float og = fminf(fmaxf(0.2f * zo + 0.5f, 0.f), 1.f);
                    float cn = fg * creg[i] + ig * ftanh(zc);
                    creg[i] = cn;
                    float hn = og * ftanh(cn);
                    int hb = (wv + 8 * i) * 4 + u_l;
                    Hbf[rr][32 + hb] = f2bf(hn);
                    Af8[rr][64 + hb] = f2f8(hn);
                }
            }
        }
        __syncthreads();

        // ========== P3: heads (waves 0-1), ks1-10 bf16, 2 dep chains ==========
        if (wv < 2) {
            f32x4 e0 = {0.f, 0.f, 0.f, 0.f}, e1 = {0.f, 0.f, 0.f, 0.f};
            #pragma unroll
            for (int ks = 1; ks < NKS; ks += 2) {
                bf16x8 a0 = *(const bf16x8*)&Hbf[arow][ks * 32 + akg * 8];
                bf16x8 b0 = *(const bf16x8*)&SW[SWH + (wv * NKS + ks) * 512 + (lane << 3)];
                e0 = MFMA(a0, b0, e0, 0, 0, 0);
                bf16x8 a1 = *(const bf16x8*)&Hbf[arow][(ks + 1) * 32 + akg * 8];
                bf16x8 b1 = *(const bf16x8*)&SW[SWH + (wv * NKS + ks + 1) * 512 + (lane << 3)];
                e1 = MFMA(a1, b1, e1, 0, 0, 0);
            }
            int col = wv * 16 + arow;
            if (col < 24) {
                #pragma unroll
                for (int rg = 0; rg < 4; ++rg)
                    Sc[crow0 + rg][col] = e0[rg] + e1[rg] + hbias;
            }
        }
        __syncthreads();

        // ========== P4: softmax/nnelu + out + next-step gate input ==========
        if (t < RPB * NFEAT) {
            float v;
            if (eA < 8) {
                float mx = Sc[rA][0];
                #pragma unroll
                for (int m = 1; m < 8; ++m) mx = fmaxf(mx, Sc[rA][m]);
                float sum = 0.f;
                #pragma unroll
                for (int m = 0; m < 8; ++m)
                    sum += __builtin_amdgcn_exp2f((Sc[rA][m] - mx) * 1.4426950408889634f);
                v = __builtin_amdgcn_exp2f((Sc[rA][eA] - mx) * 1.4426950408889634f) / sum;
            } else if (eA < 16) {
                v = Sc[rA][eA];
            } else if (eA < 24) {
                float s = Sc[rA][eA];
                v = (s > 0.f) ? (1.f + s) : __builtin_amdgcn_exp2f(s * 1.4426950408889634f);
            } else {
                v = combreg;
            }
            out[((size_t)(row0 + rA) * TT + ts) * NFEAT + eA] = v;
            if (eA < 24) {
                Gbf[rA][eA]      = f2bf(xreg);
                Gbf[rA][25 + eA] = f2bf(v);
            } else {
                float comb = xreg + combreg;
                float denom = fmaxf(comb, 1e-8f);
                Gbf[rA][24] = f2bf(xreg / denom);
                Gbf[rA][49] = f2bf(combreg / denom);
                CombS[rA] = comb;
                combreg = comb;
            }
        }
        __syncthreads();
    }
}

extern "C" void kernel_launch(void* const* d_in, const int* in_sizes, int n_in,
                              void* d_out, int out_size, void* d_ws, size_t ws_size,
                              hipStream_t stream) {
    const float* x   = (const float*)d_in[0];
    const float* wk  = (const float*)d_in[1];
    const float* wr  = (const float*)d_in[2];
    const float* bz  = (const float*)d_in[3];
    const float* w1  = (const float*)d_in[4];
    const float* b1  = (const float*)d_in[5];
    const float* w2  = (const float*)d_in[6];
    const float* b2  = (const float*)d_in[7];
    const float* wa  = (const float*)d_in[8];
    const float* ba  = (const float*)d_in[9];
    const float* wm  = (const float*)d_in[10];
    const float* bm  = (const float*)d_in[11];
    const float* wsg = (const float*)d_in[12];
    const float* bs  = (const float*)d_in[13];
    float* out = (float*)d_out;
    unsigned short* wf = (unsigned short*)d_ws;
    unsigned char*  wf8 = (unsigned char*)(wf + OFF_F8);
    float* bzdst = (float*)(wf + OFF_BZ);
    float* wkdst = (float*)(wf + OFF_WK);

    conv_b8<<<(SZ_F8B + 255) / 256, 256, 0, stream>>>(wk, wr, w2, wf8);
    conv_misc<<<(1280 + 255) / 256, 256, 0, stream>>>(wk, bz, b2, bzdst, wkdst);
    conv_gen<<<(SZ_M1 + 255) / 256, 256, 0, stream>>>(w1, wf + OFF_M1, 50, 50, 2, SZ_M1);
    conv_heads<<<(SZ_H + 255) / 256, 256, 0, stream>>>(wa, wm, wsg, wf + OFF_H);
    dilstm<<<NBLK, NT, 0, stream>>>(x, wf, b1, ba, bm, bs, out);
}